// Round 1
// baseline (634.601 us; speedup 1.0000x reference)
//
#include <hip/hip_runtime.h>
#include <math.h>

// Problem constants
#define BB   8
#define NB   300
#define RSEL 36
#define NCH  256
#define NW   10          // ceil(300/32) bitmask words
#define IOU_THR  0.7f
#define CONF_THR 0.3f

// ws layout: per (batch, slot<36): 8 floats [x1,y1,x2,y2, level, valid, pad, pad]

__global__ __launch_bounds__(256) void nms_kernel(
    const float* __restrict__ boxes, const float* __restrict__ scores,
    float* __restrict__ ws)
{
    const int b   = blockIdx.x;
    const int tid = threadIdx.x;

    __shared__ float ss[NB];            // thresholded scores, original order
    __shared__ float sbx[NB][4];        // boxes in sorted order
    __shared__ float ssv[NB];           // scores in sorted order
    __shared__ unsigned int supp[NB][NW];
    __shared__ unsigned int keepw[NW];
    __shared__ int kept_total;

    const float NEG_INF = -__builtin_inff();

    // 1) threshold scores, zero bitmasks
    for (int i = tid; i < NB; i += blockDim.x) {
        float sc = scores[b * NB + i];
        ss[i] = (sc > CONF_THR) ? sc : NEG_INF;
    }
    for (int t = tid; t < NB * NW; t += blockDim.x)
        ((unsigned int*)supp)[t] = 0u;
    if (tid < NW) keepw[tid] = 0u;
    __syncthreads();

    // 2) stable descending rank (== jnp.argsort(-s) stable, tie -> lower index first)
    for (int i = tid; i < NB; i += blockDim.x) {
        float si = ss[i];
        int r = 0;
        for (int j = 0; j < NB; ++j) {
            float sj = ss[j];
            r += (sj > si) || (sj == si && j < i);
        }
        ssv[r]    = si;
        sbx[r][0] = boxes[(b * NB + i) * 4 + 0];
        sbx[r][1] = boxes[(b * NB + i) * 4 + 1];
        sbx[r][2] = boxes[(b * NB + i) * 4 + 2];
        sbx[r][3] = boxes[(b * NB + i) * 4 + 3];
        if (si > NEG_INF) atomicOr(&keepw[r >> 5], 1u << (r & 31));
    }
    __syncthreads();

    // 3) suppression matrix: bit j of supp[i] set iff j>i and iou(i,j) > thr
    for (int t = tid; t < NB * NB; t += blockDim.x) {
        int i = t / NB, j = t % NB;
        if (j <= i) continue;
        float ax1 = sbx[i][0], ay1 = sbx[i][1], ax2 = sbx[i][2], ay2 = sbx[i][3];
        float bx1 = sbx[j][0], by1 = sbx[j][1], bx2 = sbx[j][2], by2 = sbx[j][3];
        float area_a = (ax2 - ax1) * (ay2 - ay1);
        float area_b = (bx2 - bx1) * (by2 - by1);
        float ltx = fmaxf(ax1, bx1), lty = fmaxf(ay1, by1);
        float rbx = fminf(ax2, bx2), rby = fminf(ay2, by2);
        float wx = fmaxf(rbx - ltx, 0.0f), wy = fmaxf(rby - lty, 0.0f);
        float inter = wx * wy;
        float iou = inter / (area_a + area_b - inter + 1e-9f);
        if (iou > IOU_THR) atomicOr(&supp[i][j >> 5], 1u << (j & 31));
    }
    __syncthreads();

    // 4) serial greedy (exactly the fori_loop): single thread, bitmask form
    if (tid == 0) {
        unsigned int kp[NW];
#pragma unroll
        for (int k = 0; k < NW; ++k) kp[k] = keepw[k];
        for (int i = 0; i < NB; ++i) {
            if ((kp[i >> 5] >> (i & 31)) & 1u) {
#pragma unroll
                for (int k = 0; k < NW; ++k) kp[k] &= ~supp[i][k];
            }
        }
        int tot = 0;
#pragma unroll
        for (int k = 0; k < NW; ++k) { keepw[k] = kp[k]; tot += __popc(kp[k]); }
        kept_total = tot;
    }
    __syncthreads();

    // 5) stable partition (argsort of 0/1 keys): kept first in order, then rest
    for (int i = tid; i < NB; i += blockDim.x) {
        int w = i >> 5, bt = i & 31;
        int kbit = (keepw[w] >> bt) & 1;
        int pre_kept = 0;
        for (int k = 0; k < w; ++k) pre_kept += __popc(keepw[k]);
        pre_kept += __popc(keepw[w] & ((1u << bt) - 1u));
        int pos = kbit ? pre_kept : (kept_total + (i - pre_kept));
        if (pos < RSEL) {
            float x1 = sbx[i][0], y1 = sbx[i][1], x2 = sbx[i][2], y2 = sbx[i][3];
            float dx = x2 - x1, dy = y2 - y1;
            float sz = sqrtf(fmaxf(dx * dx + dy * dy, 1e-12f));
            float l  = floorf(4.0f + log2f((sz / 224.0f) * 4.0f));
            l = fminf(fmaxf(l, 2.0f), 5.0f) - 2.0f;
            float* o = ws + (size_t)(b * RSEL + pos) * 8;
            o[0] = x1; o[1] = y1; o[2] = x2; o[3] = y2;
            o[4] = l;  o[5] = (float)kbit;
        }
    }
}

__global__ __launch_bounds__(256) void pool_kernel(
    const float* __restrict__ f0, const float* __restrict__ f1,
    const float* __restrict__ f2, const float* __restrict__ f3,
    const float* __restrict__ ws, float* __restrict__ out)
{
    const int blk = blockIdx.x;
    const int b   = blk / RSEL;
    const int r   = blk % RSEL;
    const int tid = threadIdx.x;   // channel

    const float* wsr = ws + (size_t)(b * RSEL + r) * 8;
    float x1 = wsr[0], y1 = wsr[1], x2 = wsr[2], y2 = wsr[3];
    int   lv = (int)wsr[4];
    int   valid = wsr[5] > 0.5f;

    size_t oidx = ((size_t)(b * RSEL + r)) * NCH + tid;
    if (!valid) { out[oidx] = 0.0f; return; }   // block-uniform

    const float* feat; int H;
    if      (lv == 0) { feat = f0; H = 200; }
    else if (lv == 1) { feat = f1; H = 100; }
    else if (lv == 2) { feat = f2; H = 50;  }
    else              { feat = f3; H = 25;  }
    const int W = H;

    __shared__ int   iy0[14], iy1[14], ix0[14], ix1[14];
    __shared__ float fly[14], flx[14];
    __shared__ int   oy[14], ox[14];

    if (tid < 28) {
        int k = (tid < 14) ? tid : tid - 14;
        float g = (k + 0.5f) * (1.0f / 14.0f);
        if (tid < 14) {
            float rh = fmaxf(y2 - y1, 1.0f);
            float Y  = y1 + rh * g;
            oy[k] = (Y < -1.0f) || (Y > (float)H);
            float y = fminf(fmaxf(Y, 0.0f), (float)(H - 1));
            int y0 = (int)floorf(y);
            iy0[k] = y0;
            iy1[k] = min(y0 + 1, H - 1);
            fly[k] = y - (float)y0;
        } else {
            float rw = fmaxf(x2 - x1, 1.0f);
            float X  = x1 + rw * g;
            ox[k] = (X < -1.0f) || (X > (float)W);
            float x = fminf(fmaxf(X, 0.0f), (float)(W - 1));
            int x0 = (int)floorf(x);
            ix0[k] = x0;
            ix1[k] = min(x0 + 1, W - 1);
            flx[k] = x - (float)x0;
        }
    }
    __syncthreads();

    const float* fc = feat + ((size_t)b * NCH + tid) * (size_t)(H * W);
    float acc = 0.0f;
    for (int i = 0; i < 14; ++i) {
        if (oy[i]) continue;                 // uniform across block
        const float* r0 = fc + iy0[i] * W;
        const float* r1 = fc + iy1[i] * W;
        float wy = fly[i];
        for (int j = 0; j < 14; ++j) {
            if (ox[j]) continue;             // uniform across block
            float wx = flx[j];
            float v00 = r0[ix0[j]], v01 = r0[ix1[j]];
            float v10 = r1[ix0[j]], v11 = r1[ix1[j]];
            float top = v00 + wx * (v01 - v00);
            float bot = v10 + wx * (v11 - v10);
            acc += top + wy * (bot - top);
        }
    }
    out[oidx] = acc * (1.0f / 196.0f);
}

extern "C" void kernel_launch(void* const* d_in, const int* in_sizes, int n_in,
                              void* d_out, int out_size, void* d_ws, size_t ws_size,
                              hipStream_t stream) {
    const float* boxes  = (const float*)d_in[0];
    const float* scores = (const float*)d_in[1];
    const float* f0     = (const float*)d_in[2];
    const float* f1     = (const float*)d_in[3];
    const float* f2     = (const float*)d_in[4];
    const float* f3     = (const float*)d_in[5];
    float* ws  = (float*)d_ws;
    float* out = (float*)d_out;

    nms_kernel<<<BB, 256, 0, stream>>>(boxes, scores, ws);
    pool_kernel<<<BB * RSEL, 256, 0, stream>>>(f0, f1, f2, f3, ws, out);
}

// Round 2
// 564.713 us; speedup vs baseline: 1.1238x; 1.1238x over previous
//
#include <hip/hip_runtime.h>
#include <math.h>

// Problem constants
#define BB   8
#define NB   300
#define RSEL 36
#define NCH  256
#define NW   10          // ceil(300/32) bitmask words
#define IOU_THR  0.7f
#define CONF_THR 0.3f
#define WSTR 128         // floats per (b,roi) ws record

// ws record layout (per (b, slot<36), stride WSTR floats):
//  [0] valid (1/0)   [1] level (0..3)  [2] nr (# distinct rows)
//  [3] ce (col extent, <=64)           [4] xmin
//  [8..35]  row indices (float)        [36..63] row weights (incl 1/196)
//  [64..127] dense column weights wxd[64]

__global__ __launch_bounds__(256) void nms_kernel(
    const float* __restrict__ boxes, const float* __restrict__ scores,
    float* __restrict__ ws)
{
    const int b   = blockIdx.x;
    const int tid = threadIdx.x;

    __shared__ float ss[NB];            // thresholded scores, original order
    __shared__ float sbx[NB][4];        // boxes in sorted order
    __shared__ unsigned int supp[NB][NW];
    __shared__ unsigned int keepw[NW];
    __shared__ int kept_total;

    const float NEG_INF = -__builtin_inff();

    // 1) threshold scores, zero bitmasks
    for (int i = tid; i < NB; i += blockDim.x) {
        float sc = scores[b * NB + i];
        ss[i] = (sc > CONF_THR) ? sc : NEG_INF;
    }
    for (int t = tid; t < NB * NW; t += blockDim.x)
        ((unsigned int*)supp)[t] = 0u;
    if (tid < NW) keepw[tid] = 0u;
    __syncthreads();

    // 2) stable descending rank (== jnp.argsort(-s) stable, tie -> lower index first)
    for (int i = tid; i < NB; i += blockDim.x) {
        float si = ss[i];
        int r = 0;
        for (int j = 0; j < NB; ++j) {
            float sj = ss[j];
            r += (sj > si) || (sj == si && j < i);
        }
        sbx[r][0] = boxes[(b * NB + i) * 4 + 0];
        sbx[r][1] = boxes[(b * NB + i) * 4 + 1];
        sbx[r][2] = boxes[(b * NB + i) * 4 + 2];
        sbx[r][3] = boxes[(b * NB + i) * 4 + 3];
        if (si > NEG_INF) atomicOr(&keepw[r >> 5], 1u << (r & 31));
    }
    __syncthreads();

    // 3) suppression matrix: bit j of supp[i] set iff j>i and iou(i,j) > thr
    for (int t = tid; t < NB * NB; t += blockDim.x) {
        int i = t / NB, j = t % NB;
        if (j <= i) continue;
        float ax1 = sbx[i][0], ay1 = sbx[i][1], ax2 = sbx[i][2], ay2 = sbx[i][3];
        float bx1 = sbx[j][0], by1 = sbx[j][1], bx2 = sbx[j][2], by2 = sbx[j][3];
        float area_a = (ax2 - ax1) * (ay2 - ay1);
        float area_b = (bx2 - bx1) * (by2 - by1);
        float ltx = fmaxf(ax1, bx1), lty = fmaxf(ay1, by1);
        float rbx = fminf(ax2, bx2), rby = fminf(ay2, by2);
        float wx = fmaxf(rbx - ltx, 0.0f), wy = fmaxf(rby - lty, 0.0f);
        float inter = wx * wy;
        float iou = inter / (area_a + area_b - inter + 1e-9f);
        if (iou > IOU_THR) atomicOr(&supp[i][j >> 5], 1u << (j & 31));
    }
    __syncthreads();

    // 4) serial greedy (exactly the fori_loop): single thread, bitmask form
    if (tid == 0) {
        unsigned int kp[NW];
#pragma unroll
        for (int k = 0; k < NW; ++k) kp[k] = keepw[k];
        for (int i = 0; i < NB; ++i) {
            if ((kp[i >> 5] >> (i & 31)) & 1u) {
#pragma unroll
                for (int k = 0; k < NW; ++k) kp[k] &= ~supp[i][k];
            }
        }
        int tot = 0;
#pragma unroll
        for (int k = 0; k < NW; ++k) { keepw[k] = kp[k]; tot += __popc(kp[k]); }
        kept_total = tot;
    }
    __syncthreads();

    // 5) stable partition + per-ROI separable pooling metadata
    for (int i = tid; i < NB; i += blockDim.x) {
        int w = i >> 5, bt = i & 31;
        int kbit = (keepw[w] >> bt) & 1;
        int pre_kept = 0;
        for (int k = 0; k < w; ++k) pre_kept += __popc(keepw[k]);
        pre_kept += __popc(keepw[w] & ((1u << bt) - 1u));
        int pos = kbit ? pre_kept : (kept_total + (i - pre_kept));
        if (pos >= RSEL) continue;

        float* o = ws + (size_t)(b * RSEL + pos) * WSTR;
        for (int k = 0; k < WSTR; ++k) o[k] = 0.0f;
        if (!kbit) continue;  // valid=0 already

        float bx1 = sbx[i][0], by1 = sbx[i][1], bx2 = sbx[i][2], by2 = sbx[i][3];
        float dx = bx2 - bx1, dy = by2 - by1;
        float sz = sqrtf(fmaxf(dx * dx + dy * dy, 1e-12f));
        float l  = floorf(4.0f + log2f(sz * (4.0f / 224.0f)));
        l = fminf(fmaxf(l, 2.0f), 5.0f) - 2.0f;
        int lvl = (int)l;
        int H = (lvl == 0) ? 200 : ((lvl == 1) ? 100 : ((lvl == 2) ? 50 : 25));
        float Hf = (float)H;

        o[0] = 1.0f;
        o[1] = l;

        // --- rows: dedupe + weights ---
        int ridx[28]; float rwt[28]; int nr = 0;
        float rh = fmaxf(dy, 1.0f);
        for (int s = 0; s < 14; ++s) {
            float g = (s + 0.5f) * (1.0f / 14.0f);
            float Y = by1 + rh * g;
            bool oob = (Y < -1.0f) || (Y > Hf);
            float yc = fminf(fmaxf(Y, 0.0f), Hf - 1.0f);
            int y0 = (int)floorf(yc);
            int y1i = min(y0 + 1, H - 1);
            float ly = yc - (float)y0;
            float w0 = oob ? 0.0f : (1.0f - ly);
            float w1 = oob ? 0.0f : ly;
            if (w0 != 0.0f) {
                int m = 0; for (; m < nr; ++m) if (ridx[m] == y0) break;
                if (m == nr) { ridx[nr] = y0; rwt[nr] = w0; ++nr; } else rwt[m] += w0;
            }
            if (w1 != 0.0f) {
                int m = 0; for (; m < nr; ++m) if (ridx[m] == y1i) break;
                if (m == nr) { ridx[nr] = y1i; rwt[nr] = w1; ++nr; } else rwt[m] += w1;
            }
        }
        o[2] = (float)nr;
        for (int m = 0; m < nr; ++m) {
            o[8 + m]  = (float)ridx[m];
            o[36 + m] = rwt[m] * (1.0f / 196.0f);
        }

        // --- cols: pass 1, min/max over nonzero-weight grid columns ---
        float rw = fmaxf(dx, 1.0f);
        int xmn = 1 << 30, xmx = -1;
        for (int s = 0; s < 14; ++s) {
            float g = (s + 0.5f) * (1.0f / 14.0f);
            float X = bx1 + rw * g;
            bool oob = (X < -1.0f) || (X > Hf);
            if (oob) continue;
            float xc = fminf(fmaxf(X, 0.0f), Hf - 1.0f);
            int x0 = (int)floorf(xc);
            int x1i = min(x0 + 1, H - 1);
            float lx = xc - (float)x0;
            if ((1.0f - lx) != 0.0f) { xmn = min(xmn, x0);  xmx = max(xmx, x0);  }
            if (lx != 0.0f)          { xmn = min(xmn, x1i); xmx = max(xmx, x1i); }
        }
        int ce = (xmx >= xmn) ? (xmx - xmn + 1) : 0;
        if (ce > 64) ce = 64;   // defensive; analysis bounds ce <= 57
        o[3] = (float)ce;
        o[4] = (float)xmn;

        // --- cols: pass 2, accumulate dense column weights ---
        if (ce > 0) {
            for (int s = 0; s < 14; ++s) {
                float g = (s + 0.5f) * (1.0f / 14.0f);
                float X = bx1 + rw * g;
                bool oob = (X < -1.0f) || (X > Hf);
                if (oob) continue;
                float xc = fminf(fmaxf(X, 0.0f), Hf - 1.0f);
                int x0 = (int)floorf(xc);
                int x1i = min(x0 + 1, H - 1);
                float lx = xc - (float)x0;
                float w0 = 1.0f - lx;
                if (w0 != 0.0f) { int p = x0 - xmn;  if (p >= 0 && p < 64) o[64 + p] += w0; }
                if (lx != 0.0f) { int p = x1i - xmn; if (p >= 0 && p < 64) o[64 + p] += lx; }
            }
        }
    }
}

// grid: (BB*RSEL, 4); block: 256. Block (br, cg) handles channels [cg*64, cg*64+64).
// Wave w of the block accumulates 16 channels; one coalesced row-segment load
// per (row, channel) since col extent <= 57 < 64 lanes.
__global__ __launch_bounds__(256) void pool_kernel(
    const float* __restrict__ f0, const float* __restrict__ f1,
    const float* __restrict__ f2, const float* __restrict__ f3,
    const float* __restrict__ ws, float* __restrict__ out)
{
    const int br   = blockIdx.x;           // b*RSEL + r
    const int cg   = blockIdx.y;           // 0..3
    const int b    = br / RSEL;
    const int tid  = threadIdx.x;
    const int lane = tid & 63;
    const int wv   = tid >> 6;

    __shared__ float smeta[WSTR];
    for (int t = tid; t < WSTR; t += 256) smeta[t] = ws[(size_t)br * WSTR + t];
    __syncthreads();

    const size_t obase = (size_t)br * NCH + (size_t)cg * 64;
    if (smeta[0] == 0.0f) {
        if (tid < 64) out[obase + tid] = 0.0f;
        return;
    }

    const int lvl = (int)smeta[1];
    const int nr  = (int)smeta[2];
    const int ce  = (int)smeta[3];
    const int xmn = (int)smeta[4];

    const float* feat; int H;
    if      (lvl == 0) { feat = f0; H = 200; }
    else if (lvl == 1) { feat = f1; H = 100; }
    else if (lvl == 2) { feat = f2; H = 50;  }
    else               { feat = f3; H = 25;  }
    const int W = H;
    const size_t cstr = (size_t)H * W;

    const bool  ld  = (lane < ce);
    const float wxl = ld ? smeta[64 + lane] : 0.0f;

    const int c0 = cg * 64 + wv * 16;
    const float* fb = feat + ((size_t)b * NCH + c0) * cstr + xmn + lane;

    float acc[16];
#pragma unroll
    for (int u = 0; u < 16; ++u) acc[u] = 0.0f;

    for (int r = 0; r < nr; ++r) {
        int   row = (int)smeta[8 + r];
        float rwt = smeta[36 + r];
        const float* p = fb + (size_t)row * W;
#pragma unroll
        for (int u = 0; u < 16; ++u) {
            float v = 0.0f;
            if (ld) v = p[u * cstr];
            acc[u] = fmaf(rwt, v, acc[u]);
        }
    }

#pragma unroll
    for (int u = 0; u < 16; ++u) {
        float a = acc[u] * wxl;
        for (int off = 32; off; off >>= 1) a += __shfl_xor(a, off, 64);
        if (lane == 0) out[obase + wv * 16 + u] = a;
    }
}

extern "C" void kernel_launch(void* const* d_in, const int* in_sizes, int n_in,
                              void* d_out, int out_size, void* d_ws, size_t ws_size,
                              hipStream_t stream) {
    const float* boxes  = (const float*)d_in[0];
    const float* scores = (const float*)d_in[1];
    const float* f0     = (const float*)d_in[2];
    const float* f1     = (const float*)d_in[3];
    const float* f2     = (const float*)d_in[4];
    const float* f3     = (const float*)d_in[5];
    float* ws  = (float*)d_ws;
    float* out = (float*)d_out;

    nms_kernel<<<BB, 256, 0, stream>>>(boxes, scores, ws);
    dim3 pgrid(BB * RSEL, 4);
    pool_kernel<<<pgrid, 256, 0, stream>>>(f0, f1, f2, f3, ws, out);
}

// Round 3
// 555.824 us; speedup vs baseline: 1.1417x; 1.0160x over previous
//
#include <hip/hip_runtime.h>
#include <math.h>

// Problem constants
#define BB   8
#define NB   300
#define RSEL 36
#define NCH  256
#define NW   10          // ceil(300/32) bitmask words
#define IOU_THR  0.7f
#define CONF_THR 0.3f
#define WSTR 128         // floats per (b,roi) ws record

// ws record layout (per (b, slot<36), stride WSTR floats):
//  [0] valid (1/0)   [1] level (0..3)  [2] nr (# distinct rows)
//  [3] ce (col extent, <=64)           [4] xmin
//  [8..35]  row indices (float)        [36..63] row weights (incl 1/196)
//  [64..127] dense column weights wxd[64]

#define NMS_T 1024

__global__ __launch_bounds__(NMS_T) void nms_kernel(
    const float* __restrict__ boxes, const float* __restrict__ scores,
    float* __restrict__ ws)
{
    const int b   = blockIdx.x;
    const int tid = threadIdx.x;

    __shared__ float ss[NB];            // thresholded scores, original order
    __shared__ float sbx[NB][4];        // boxes in sorted order
    __shared__ unsigned int supp[NB][NW];
    __shared__ unsigned int keepw[NW];
    __shared__ int kept_total;

    const float NEG_INF = -__builtin_inff();

    // 0) cooperative zero of this batch's ws records (global, coalesced)
    {
        float* wb = ws + (size_t)b * RSEL * WSTR;
        for (int t = tid; t < RSEL * WSTR; t += NMS_T) wb[t] = 0.0f;
    }

    // 1) threshold scores, zero bitmasks
    for (int i = tid; i < NB; i += NMS_T) {
        float sc = scores[b * NB + i];
        ss[i] = (sc > CONF_THR) ? sc : NEG_INF;
    }
    for (int t = tid; t < NB * NW; t += NMS_T)
        ((unsigned int*)supp)[t] = 0u;
    if (tid < NW) keepw[tid] = 0u;
    __syncthreads();

    // 2) stable descending rank (== jnp.argsort(-s) stable, tie -> lower index first)
    for (int i = tid; i < NB; i += NMS_T) {
        float si = ss[i];
        int r = 0;
        for (int j = 0; j < NB; ++j) {
            float sj = ss[j];
            r += (sj > si) || (sj == si && j < i);
        }
        sbx[r][0] = boxes[(b * NB + i) * 4 + 0];
        sbx[r][1] = boxes[(b * NB + i) * 4 + 1];
        sbx[r][2] = boxes[(b * NB + i) * 4 + 2];
        sbx[r][3] = boxes[(b * NB + i) * 4 + 3];
        if (si > NEG_INF) atomicOr(&keepw[r >> 5], 1u << (r & 31));
    }
    __syncthreads();

    // 3) suppression matrix: bit j of supp[i] set iff j>i and iou(i,j) > thr
    for (int t = tid; t < NB * NB; t += NMS_T) {
        int i = t / NB, j = t - i * NB;
        if (j <= i) continue;
        float ax1 = sbx[i][0], ay1 = sbx[i][1], ax2 = sbx[i][2], ay2 = sbx[i][3];
        float bx1 = sbx[j][0], by1 = sbx[j][1], bx2 = sbx[j][2], by2 = sbx[j][3];
        float area_a = (ax2 - ax1) * (ay2 - ay1);
        float area_b = (bx2 - bx1) * (by2 - by1);
        float ltx = fmaxf(ax1, bx1), lty = fmaxf(ay1, by1);
        float rbx = fminf(ax2, bx2), rby = fminf(ay2, by2);
        float wx = fmaxf(rbx - ltx, 0.0f), wy = fmaxf(rby - lty, 0.0f);
        float inter = wx * wy;
        float iou = inter / (area_a + area_b - inter + 1e-9f);
        if (iou > IOU_THR) atomicOr(&supp[i][j >> 5], 1u << (j & 31));
    }
    __syncthreads();

    // 4) greedy suppression scan, wave-parallel bitmask form (wave 0).
    // lane w (<NW) owns keep-word w; keep-bit of i is broadcast by shuffle.
    // Branch is wave-uniform (wrd is identical across lanes).
    if (tid < 64) {
        const int lane = tid;
        unsigned int kpw = (lane < NW) ? keepw[lane] : 0u;
        for (int i = 0; i < NB; ++i) {
            unsigned int wrd = __shfl(kpw, i >> 5, 64);
            if ((wrd >> (i & 31)) & 1u) {
                unsigned int s = (lane < NW) ? supp[i][lane] : 0u;
                kpw &= ~s;
            }
        }
        if (lane < NW) keepw[lane] = kpw;
        int tot = (lane < NW) ? __popc(kpw) : 0;
        for (int off = 32; off; off >>= 1) tot += __shfl_xor(tot, off, 64);
        if (lane == 0) kept_total = tot;
    }
    __syncthreads();

    // 5) stable partition + per-ROI separable pooling metadata
    for (int i = tid; i < NB; i += NMS_T) {
        int w = i >> 5, bt = i & 31;
        int kbit = (keepw[w] >> bt) & 1;
        int pre_kept = 0;
        for (int k = 0; k < w; ++k) pre_kept += __popc(keepw[k]);
        pre_kept += __popc(keepw[w] & ((1u << bt) - 1u));
        int pos = kbit ? pre_kept : (kept_total + (i - pre_kept));
        if (pos >= RSEL) continue;
        if (!kbit) continue;  // record already zeroed -> valid=0

        float* o = ws + (size_t)(b * RSEL + pos) * WSTR;

        float bx1 = sbx[i][0], by1 = sbx[i][1], bx2 = sbx[i][2], by2 = sbx[i][3];
        float dx = bx2 - bx1, dy = by2 - by1;
        float sz = sqrtf(fmaxf(dx * dx + dy * dy, 1e-12f));
        float l  = floorf(4.0f + log2f(sz * (4.0f / 224.0f)));
        l = fminf(fmaxf(l, 2.0f), 5.0f) - 2.0f;
        int lvl = (int)l;
        int H = (lvl == 0) ? 200 : ((lvl == 1) ? 100 : ((lvl == 2) ? 50 : 25));
        float Hf = (float)H;

        o[0] = 1.0f;
        o[1] = l;

        // --- rows: dedupe + weights ---
        int ridx[28]; float rwt[28]; int nr = 0;
        float rh = fmaxf(dy, 1.0f);
        for (int s = 0; s < 14; ++s) {
            float g = (s + 0.5f) * (1.0f / 14.0f);
            float Y = by1 + rh * g;
            bool oob = (Y < -1.0f) || (Y > Hf);
            float yc = fminf(fmaxf(Y, 0.0f), Hf - 1.0f);
            int y0 = (int)floorf(yc);
            int y1i = min(y0 + 1, H - 1);
            float ly = yc - (float)y0;
            float w0 = oob ? 0.0f : (1.0f - ly);
            float w1 = oob ? 0.0f : ly;
            if (w0 != 0.0f) {
                int m = 0; for (; m < nr; ++m) if (ridx[m] == y0) break;
                if (m == nr) { ridx[nr] = y0; rwt[nr] = w0; ++nr; } else rwt[m] += w0;
            }
            if (w1 != 0.0f) {
                int m = 0; for (; m < nr; ++m) if (ridx[m] == y1i) break;
                if (m == nr) { ridx[nr] = y1i; rwt[nr] = w1; ++nr; } else rwt[m] += w1;
            }
        }
        o[2] = (float)nr;
        for (int m = 0; m < nr; ++m) {
            o[8 + m]  = (float)ridx[m];
            o[36 + m] = rwt[m] * (1.0f / 196.0f);
        }

        // --- cols: pass 1, min/max over nonzero-weight grid columns ---
        float rw = fmaxf(dx, 1.0f);
        int xmn = 1 << 30, xmx = -1;
        for (int s = 0; s < 14; ++s) {
            float g = (s + 0.5f) * (1.0f / 14.0f);
            float X = bx1 + rw * g;
            bool oob = (X < -1.0f) || (X > Hf);
            if (oob) continue;
            float xc = fminf(fmaxf(X, 0.0f), Hf - 1.0f);
            int x0 = (int)floorf(xc);
            int x1i = min(x0 + 1, H - 1);
            float lx = xc - (float)x0;
            if ((1.0f - lx) != 0.0f) { xmn = min(xmn, x0);  xmx = max(xmx, x0);  }
            if (lx != 0.0f)          { xmn = min(xmn, x1i); xmx = max(xmx, x1i); }
        }
        int ce = (xmx >= xmn) ? (xmx - xmn + 1) : 0;
        if (ce > 64) ce = 64;   // defensive; analysis bounds ce <= 57
        o[3] = (float)ce;
        o[4] = (float)xmn;

        // --- cols: pass 2, accumulate dense column weights ---
        if (ce > 0) {
            for (int s = 0; s < 14; ++s) {
                float g = (s + 0.5f) * (1.0f / 14.0f);
                float X = bx1 + rw * g;
                bool oob = (X < -1.0f) || (X > Hf);
                if (oob) continue;
                float xc = fminf(fmaxf(X, 0.0f), Hf - 1.0f);
                int x0 = (int)floorf(xc);
                int x1i = min(x0 + 1, H - 1);
                float lx = xc - (float)x0;
                float w0 = 1.0f - lx;
                if (w0 != 0.0f) { int p = x0 - xmn;  if (p >= 0 && p < 64) o[64 + p] += w0; }
                if (lx != 0.0f) { int p = x1i - xmn; if (p >= 0 && p < 64) o[64 + p] += lx; }
            }
        }
    }
}

// grid: (BB*RSEL, 4); block: 256. Block (br, cg) handles channels [cg*64, cg*64+64).
// Wave w of the block accumulates 16 channels; one coalesced row-segment load
// per (row, channel) since col extent <= 57 < 64 lanes.
__global__ __launch_bounds__(256) void pool_kernel(
    const float* __restrict__ f0, const float* __restrict__ f1,
    const float* __restrict__ f2, const float* __restrict__ f3,
    const float* __restrict__ ws, float* __restrict__ out)
{
    const int br   = blockIdx.x;           // b*RSEL + r
    const int cg   = blockIdx.y;           // 0..3
    const int b    = br / RSEL;
    const int tid  = threadIdx.x;
    const int lane = tid & 63;
    const int wv   = tid >> 6;

    __shared__ float smeta[WSTR];
    for (int t = tid; t < WSTR; t += 256) smeta[t] = ws[(size_t)br * WSTR + t];
    __syncthreads();

    const size_t obase = (size_t)br * NCH + (size_t)cg * 64;
    if (smeta[0] == 0.0f) {
        if (tid < 64) out[obase + tid] = 0.0f;
        return;
    }

    const int lvl = (int)smeta[1];
    const int nr  = (int)smeta[2];
    const int ce  = (int)smeta[3];
    const int xmn = (int)smeta[4];

    const float* feat; int H;
    if      (lvl == 0) { feat = f0; H = 200; }
    else if (lvl == 1) { feat = f1; H = 100; }
    else if (lvl == 2) { feat = f2; H = 50;  }
    else               { feat = f3; H = 25;  }
    const int W = H;
    const size_t cstr = (size_t)H * W;

    const bool  ld  = (lane < ce);
    const float wxl = ld ? smeta[64 + lane] : 0.0f;

    const int c0 = cg * 64 + wv * 16;
    const float* fb = feat + ((size_t)b * NCH + c0) * cstr + xmn + lane;

    float acc[16];
#pragma unroll
    for (int u = 0; u < 16; ++u) acc[u] = 0.0f;

    for (int r = 0; r < nr; ++r) {
        int   row = (int)smeta[8 + r];
        float rwt = smeta[36 + r];
        const float* p = fb + (size_t)row * W;
#pragma unroll
        for (int u = 0; u < 16; ++u) {
            float v = 0.0f;
            if (ld) v = p[u * cstr];
            acc[u] = fmaf(rwt, v, acc[u]);
        }
    }

#pragma unroll
    for (int u = 0; u < 16; ++u) {
        float a = acc[u] * wxl;
        for (int off = 32; off; off >>= 1) a += __shfl_xor(a, off, 64);
        if (lane == 0) out[obase + wv * 16 + u] = a;
    }
}

extern "C" void kernel_launch(void* const* d_in, const int* in_sizes, int n_in,
                              void* d_out, int out_size, void* d_ws, size_t ws_size,
                              hipStream_t stream) {
    const float* boxes  = (const float*)d_in[0];
    const float* scores = (const float*)d_in[1];
    const float* f0     = (const float*)d_in[2];
    const float* f1     = (const float*)d_in[3];
    const float* f2     = (const float*)d_in[4];
    const float* f3     = (const float*)d_in[5];
    float* ws  = (float*)d_ws;
    float* out = (float*)d_out;

    nms_kernel<<<BB, NMS_T, 0, stream>>>(boxes, scores, ws);
    dim3 pgrid(BB * RSEL, 4);
    pool_kernel<<<pgrid, 256, 0, stream>>>(f0, f1, f2, f3, ws, out);
}

// Round 4
// 554.120 us; speedup vs baseline: 1.1452x; 1.0031x over previous
//
#include <hip/hip_runtime.h>
#include <math.h>

// Problem constants
#define BB   8
#define NB   300
#define RSEL 36
#define NCH  256
#define NW   10          // ceil(300/32) bitmask words
#define IOU_THR  0.7f
#define CONF_THR 0.3f
#define WSTR 128         // floats per (b,roi) ws record

// ws record layout (per (b, slot<36), stride WSTR floats):
//  [0] valid (1/0)   [1] level (0..3)  [2] nr (# distinct rows)
//  [3] ce (col extent, <=64)           [4] xmin
//  [8..35]  row indices (float)        [36..63] row weights (incl 1/196)
//  [64..127] dense column weights wxd[64]

#define NMS_T 1024

__global__ __launch_bounds__(NMS_T) void nms_kernel(
    const float* __restrict__ boxes, const float* __restrict__ scores,
    float* __restrict__ ws)
{
    const int b   = blockIdx.x;
    const int tid = threadIdx.x;

    __shared__ float ss[NB];            // thresholded scores, original order
    __shared__ float sbx[NB][4];        // boxes in sorted order
    __shared__ unsigned int supp[NB][NW];
    __shared__ unsigned int keepw[NW];
    __shared__ int kept_total;

    const float NEG_INF = -__builtin_inff();

    // 0) cooperative zero of this batch's ws records (global, coalesced)
    {
        float* wb = ws + (size_t)b * RSEL * WSTR;
        for (int t = tid; t < RSEL * WSTR; t += NMS_T) wb[t] = 0.0f;
    }

    // 1) threshold scores, zero bitmasks
    for (int i = tid; i < NB; i += NMS_T) {
        float sc = scores[b * NB + i];
        ss[i] = (sc > CONF_THR) ? sc : NEG_INF;
    }
    for (int t = tid; t < NB * NW; t += NMS_T)
        ((unsigned int*)supp)[t] = 0u;
    if (tid < NW) keepw[tid] = 0u;
    __syncthreads();

    // 2) stable descending rank (== jnp.argsort(-s) stable, tie -> lower index first)
    for (int i = tid; i < NB; i += NMS_T) {
        float si = ss[i];
        int r = 0;
        for (int j = 0; j < NB; ++j) {
            float sj = ss[j];
            r += (sj > si) || (sj == si && j < i);
        }
        sbx[r][0] = boxes[(b * NB + i) * 4 + 0];
        sbx[r][1] = boxes[(b * NB + i) * 4 + 1];
        sbx[r][2] = boxes[(b * NB + i) * 4 + 2];
        sbx[r][3] = boxes[(b * NB + i) * 4 + 3];
        if (si > NEG_INF) atomicOr(&keepw[r >> 5], 1u << (r & 31));
    }
    __syncthreads();

    // 3) suppression matrix: bit j of supp[i] set iff j>i and iou(i,j) > thr
    for (int t = tid; t < NB * NB; t += NMS_T) {
        int i = t / NB, j = t - i * NB;
        if (j <= i) continue;
        float ax1 = sbx[i][0], ay1 = sbx[i][1], ax2 = sbx[i][2], ay2 = sbx[i][3];
        float bx1 = sbx[j][0], by1 = sbx[j][1], bx2 = sbx[j][2], by2 = sbx[j][3];
        float area_a = (ax2 - ax1) * (ay2 - ay1);
        float area_b = (bx2 - bx1) * (by2 - by1);
        float ltx = fmaxf(ax1, bx1), lty = fmaxf(ay1, by1);
        float rbx = fminf(ax2, bx2), rby = fminf(ay2, by2);
        float wx = fmaxf(rbx - ltx, 0.0f), wy = fmaxf(rby - lty, 0.0f);
        float inter = wx * wy;
        float iou = inter / (area_a + area_b - inter + 1e-9f);
        if (iou > IOU_THR) atomicOr(&supp[i][j >> 5], 1u << (j & 31));
    }
    __syncthreads();

    // 4) greedy suppression scan, wave-parallel bitmask form (wave 0).
    if (tid < 64) {
        const int lane = tid;
        unsigned int kpw = (lane < NW) ? keepw[lane] : 0u;
        for (int i = 0; i < NB; ++i) {
            unsigned int wrd = __shfl(kpw, i >> 5, 64);
            if ((wrd >> (i & 31)) & 1u) {
                unsigned int s = (lane < NW) ? supp[i][lane] : 0u;
                kpw &= ~s;
            }
        }
        if (lane < NW) keepw[lane] = kpw;
        int tot = (lane < NW) ? __popc(kpw) : 0;
        for (int off = 32; off; off >>= 1) tot += __shfl_xor(tot, off, 64);
        if (lane == 0) kept_total = tot;
    }
    __syncthreads();

    // 5) stable partition + per-ROI separable pooling metadata
    for (int i = tid; i < NB; i += NMS_T) {
        int w = i >> 5, bt = i & 31;
        int kbit = (keepw[w] >> bt) & 1;
        int pre_kept = 0;
        for (int k = 0; k < w; ++k) pre_kept += __popc(keepw[k]);
        pre_kept += __popc(keepw[w] & ((1u << bt) - 1u));
        int pos = kbit ? pre_kept : (kept_total + (i - pre_kept));
        if (pos >= RSEL) continue;
        if (!kbit) continue;  // record already zeroed -> valid=0

        float* o = ws + (size_t)(b * RSEL + pos) * WSTR;

        float bx1 = sbx[i][0], by1 = sbx[i][1], bx2 = sbx[i][2], by2 = sbx[i][3];
        float dx = bx2 - bx1, dy = by2 - by1;
        float sz = sqrtf(fmaxf(dx * dx + dy * dy, 1e-12f));
        float l  = floorf(4.0f + log2f(sz * (4.0f / 224.0f)));
        l = fminf(fmaxf(l, 2.0f), 5.0f) - 2.0f;
        int lvl = (int)l;
        int H = (lvl == 0) ? 200 : ((lvl == 1) ? 100 : ((lvl == 2) ? 50 : 25));
        float Hf = (float)H;

        o[0] = 1.0f;
        o[1] = l;

        // --- rows: dedupe + weights ---
        int ridx[28]; float rwt[28]; int nr = 0;
        float rh = fmaxf(dy, 1.0f);
        for (int s = 0; s < 14; ++s) {
            float g = (s + 0.5f) * (1.0f / 14.0f);
            float Y = by1 + rh * g;
            bool oob = (Y < -1.0f) || (Y > Hf);
            float yc = fminf(fmaxf(Y, 0.0f), Hf - 1.0f);
            int y0 = (int)floorf(yc);
            int y1i = min(y0 + 1, H - 1);
            float ly = yc - (float)y0;
            float w0 = oob ? 0.0f : (1.0f - ly);
            float w1 = oob ? 0.0f : ly;
            if (w0 != 0.0f) {
                int m = 0; for (; m < nr; ++m) if (ridx[m] == y0) break;
                if (m == nr) { ridx[nr] = y0; rwt[nr] = w0; ++nr; } else rwt[m] += w0;
            }
            if (w1 != 0.0f) {
                int m = 0; for (; m < nr; ++m) if (ridx[m] == y1i) break;
                if (m == nr) { ridx[nr] = y1i; rwt[nr] = w1; ++nr; } else rwt[m] += w1;
            }
        }
        o[2] = (float)nr;
        for (int m = 0; m < nr; ++m) {
            o[8 + m]  = (float)ridx[m];
            o[36 + m] = rwt[m] * (1.0f / 196.0f);
        }

        // --- cols: pass 1, min/max over nonzero-weight grid columns ---
        float rw = fmaxf(dx, 1.0f);
        int xmn = 1 << 30, xmx = -1;
        for (int s = 0; s < 14; ++s) {
            float g = (s + 0.5f) * (1.0f / 14.0f);
            float X = bx1 + rw * g;
            bool oob = (X < -1.0f) || (X > Hf);
            if (oob) continue;
            float xc = fminf(fmaxf(X, 0.0f), Hf - 1.0f);
            int x0 = (int)floorf(xc);
            int x1i = min(x0 + 1, H - 1);
            float lx = xc - (float)x0;
            if ((1.0f - lx) != 0.0f) { xmn = min(xmn, x0);  xmx = max(xmx, x0);  }
            if (lx != 0.0f)          { xmn = min(xmn, x1i); xmx = max(xmx, x1i); }
        }
        int ce = (xmx >= xmn) ? (xmx - xmn + 1) : 0;
        if (ce > 64) ce = 64;   // defensive; analysis bounds ce <= 57
        o[3] = (float)ce;
        o[4] = (float)xmn;

        // --- cols: pass 2, accumulate dense column weights ---
        if (ce > 0) {
            for (int s = 0; s < 14; ++s) {
                float g = (s + 0.5f) * (1.0f / 14.0f);
                float X = bx1 + rw * g;
                bool oob = (X < -1.0f) || (X > Hf);
                if (oob) continue;
                float xc = fminf(fmaxf(X, 0.0f), Hf - 1.0f);
                int x0 = (int)floorf(xc);
                int x1i = min(x0 + 1, H - 1);
                float lx = xc - (float)x0;
                float w0 = 1.0f - lx;
                if (w0 != 0.0f) { int p = x0 - xmn;  if (p >= 0 && p < 64) o[64 + p] += w0; }
                if (lx != 0.0f) { int p = x1i - xmn; if (p >= 0 && p < 64) o[64 + p] += lx; }
            }
        }
    }
}

// grid: (BB*RSEL, 4); block: 256. Block (br, cg) handles channels [cg*64, cg*64+64).
// Wave w accumulates 16 channels. Row-packing: pack = 4 rows/round if ce<=16,
// 2 if ce<=32, else 1; lane = h*cpl + c covers (row r+h, col c). Row weight is
// folded into the per-lane FMA scalar; the 64-lane reduction sums rows x cols.
__global__ __launch_bounds__(256) void pool_kernel(
    const float* __restrict__ f0, const float* __restrict__ f1,
    const float* __restrict__ f2, const float* __restrict__ f3,
    const float* __restrict__ ws, float* __restrict__ out)
{
    const int br   = blockIdx.x;           // b*RSEL + r
    const int cg   = blockIdx.y;           // 0..3
    const int b    = br / RSEL;
    const int tid  = threadIdx.x;
    const int lane = tid & 63;
    const int wv   = tid >> 6;

    __shared__ float smeta[WSTR];
    for (int t = tid; t < WSTR; t += 256) smeta[t] = ws[(size_t)br * WSTR + t];
    __syncthreads();

    const size_t obase = (size_t)br * NCH + (size_t)cg * 64;
    if (smeta[0] == 0.0f) {
        if (tid < 64) out[obase + tid] = 0.0f;
        return;
    }

    const int lvl = (int)smeta[1];
    const int nr  = (int)smeta[2];
    const int ce  = (int)smeta[3];
    const int xmn = (int)smeta[4];

    const float* feat; int H;
    if      (lvl == 0) { feat = f0; H = 200; }
    else if (lvl == 1) { feat = f1; H = 100; }
    else if (lvl == 2) { feat = f2; H = 50;  }
    else               { feat = f3; H = 25;  }
    const int W = H;
    const size_t cstr = (size_t)H * W;

    // Row-packing factor (uniform across block).
    const int pack = (ce <= 16) ? 4 : ((ce <= 32) ? 2 : 1);
    const int cpl  = 64 / pack;            // cols per row-slot: 16/32/64
    const int c    = lane & (cpl - 1);
    const int h    = lane / cpl;           // row slot within round

    const bool  cld = (c < ce);
    const float wxl = cld ? smeta[64 + c] : 0.0f;

    const int c0 = cg * 64 + wv * 16;
    const float* fb = feat + ((size_t)b * NCH + c0) * cstr + xmn + c;

    float acc[16];
#pragma unroll
    for (int u = 0; u < 16; ++u) acc[u] = 0.0f;

    for (int r = 0; r < nr; r += pack) {
        const int  rh   = r + h;
        const bool rok  = (rh < nr);
        const int  row  = rok ? (int)smeta[8 + rh] : 0;
        const float rwt = rok ? smeta[36 + rh] : 0.0f;
        const float* p  = fb + (size_t)row * W;
#pragma unroll
        for (int u = 0; u < 16; ++u) {
            float v = 0.0f;
            if (cld) v = p[u * cstr];
            acc[u] = fmaf(rwt, v, acc[u]);
        }
    }

#pragma unroll
    for (int u = 0; u < 16; ++u) {
        float a = acc[u] * wxl;
        for (int off = 32; off; off >>= 1) a += __shfl_xor(a, off, 64);
        if (lane == 0) out[obase + wv * 16 + u] = a;
    }
}

extern "C" void kernel_launch(void* const* d_in, const int* in_sizes, int n_in,
                              void* d_out, int out_size, void* d_ws, size_t ws_size,
                              hipStream_t stream) {
    const float* boxes  = (const float*)d_in[0];
    const float* scores = (const float*)d_in[1];
    const float* f0     = (const float*)d_in[2];
    const float* f1     = (const float*)d_in[3];
    const float* f2     = (const float*)d_in[4];
    const float* f3     = (const float*)d_in[5];
    float* ws  = (float*)d_ws;
    float* out = (float*)d_out;

    nms_kernel<<<BB, NMS_T, 0, stream>>>(boxes, scores, ws);
    dim3 pgrid(BB * RSEL, 4);
    pool_kernel<<<pgrid, 256, 0, stream>>>(f0, f1, f2, f3, ws, out);
}